// Round 1
// baseline (1217.677 us; speedup 1.0000x reference)
//
#include <hip/hip_runtime.h>
#include <math.h>

#define NN 10000
#define NE 160000
#define NG 64
#define DIM 32

__device__ __forceinline__ float sigmoidf_(float x) { return 1.f / (1.f + expf(-x)); }

// ---------------------------------------------------------------- CSR build
__global__ void k_count(const int* __restrict__ ei, int* __restrict__ cnt) {
    int e = blockIdx.x * 256 + threadIdx.x;
    if (e < NE) atomicAdd(&cnt[ei[NE + e]], 1);
}

__global__ void k_scan(const int* __restrict__ cnt, int* __restrict__ row_start,
                       float* __restrict__ deg) {
    __shared__ int sums[256];
    int t = threadIdx.x;
    const int chunk = (NN + 255) / 256;   // 40
    int begin = t * chunk;
    int end = begin + chunk; if (end > NN) end = NN;
    int s = 0;
    for (int i = begin; i < end; ++i) s += cnt[i];
    sums[t] = s;
    __syncthreads();
    if (t == 0) {
        int acc = 0;
        for (int i = 0; i < 256; ++i) { int v = sums[i]; sums[i] = acc; acc += v; }
        row_start[NN] = acc;   // == NE
    }
    __syncthreads();
    int acc = sums[t];
    for (int i = begin; i < end; ++i) {
        row_start[i] = acc;
        int c = cnt[i];
        deg[i] = (float)(c > 0 ? c : 1);
        acc += c;
    }
}

__global__ void k_fill(const int* __restrict__ ei, const int* __restrict__ row_start,
                       int* __restrict__ cursor, int* __restrict__ eidx) {
    int e = blockIdx.x * 256 + threadIdx.x;
    if (e >= NE) return;
    int d = ei[NE + e];
    int p = atomicAdd(&cursor[d], 1);
    eidx[row_start[d] + p] = e;
}

__global__ void k_gstart(const int* __restrict__ batch, int* __restrict__ gstart) {
    int g = threadIdx.x;
    if (g > NG) return;
    int lo = 0, hi = NN;
    while (lo < hi) { int mid = (lo + hi) >> 1; if (batch[mid] < g) lo = mid + 1; else hi = mid; }
    gstart[g] = lo;
}

// W2 (128,1024) row-major [h][i*32+o]  ->  w2t [o][i][h]  (o*4096 + i*128 + h)
__global__ void k_w2t(const float* __restrict__ w2, float* __restrict__ w2t) {
    int idx = blockIdx.x * 256 + threadIdx.x;   // < 131072
    int h = idx >> 10, rem = idx & 1023, i = rem >> 5, o = rem & 31;
    w2t[o * 4096 + i * 128 + h] = w2[idx];
}

__global__ void k_lin0(const float* __restrict__ x, const float* __restrict__ w,
                       const float* __restrict__ b, float* __restrict__ out) {
    int idx = blockIdx.x * 256 + threadIdx.x;   // < NN*DIM
    int n = idx >> 5, d = idx & 31;
    out[idx] = fmaxf(x[n] * w[d] + b[d], 0.f);
}

// ---------------------------------------------------------------- NNConv
// Per block: 4 nodes (one per wave). Edge phase: lane owns h=lane, h=lane+64;
// accumulates R[h][i] over incoming edges in 64 registers. Contraction:
// agg[o] = (sum_{h,i} R[h,i]*W2[h,i,o] + sum_i S[i]*b2[i,o]) / deg.
__global__ __launch_bounds__(256) void k_conv(
    const int* __restrict__ row_start, const int* __restrict__ eidx,
    const int* __restrict__ ei, const float* __restrict__ ea,
    const float* __restrict__ w1, const float* __restrict__ b1,
    const float* __restrict__ w2t, const float* __restrict__ b2,
    const float* __restrict__ out, const float* __restrict__ deg,
    float* __restrict__ Sg, float* __restrict__ agg)
{
    __shared__ float R[4 * 32 * 128];   // [nb][i][h] = 64 KB exactly
    int t = threadIdx.x;
    int wave = t >> 6, lane = t & 63;
    int n0 = blockIdx.x * 4;
    int n = n0 + wave;

    float Racc[64];
    #pragma unroll
    for (int i = 0; i < 64; ++i) Racc[i] = 0.f;
    float sacc = 0.f;

    // hoisted first-layer weights for h = lane and h = lane+64
    float w1a0 = w1[lane],      w1c0 = w1[128 + lane],  bb0 = b1[lane];
    float w1a1 = w1[64 + lane], w1c1 = w1[192 + lane],  bb1 = b1[64 + lane];

    int rs = row_start[n], re = row_start[n + 1];
    for (int p = rs; p < re; ++p) {
        int e = eidx[p];
        int src = ei[e];
        float a0 = ea[2 * e], a1 = ea[2 * e + 1];
        float r0 = fmaxf(a0 * w1a0 + a1 * w1c0 + bb0, 0.f);
        float r1 = fmaxf(a0 * w1a1 + a1 * w1c1 + bb1, 0.f);
        const float4* op = (const float4*)(out + src * DIM);
        #pragma unroll
        for (int q = 0; q < 8; ++q) {
            float4 o4 = op[q];
            Racc[4 * q + 0]      += r0 * o4.x;
            Racc[4 * q + 1]      += r0 * o4.y;
            Racc[4 * q + 2]      += r0 * o4.z;
            Racc[4 * q + 3]      += r0 * o4.w;
            Racc[32 + 4 * q + 0] += r1 * o4.x;
            Racc[32 + 4 * q + 1] += r1 * o4.y;
            Racc[32 + 4 * q + 2] += r1 * o4.z;
            Racc[32 + 4 * q + 3] += r1 * o4.w;
        }
        if (lane < DIM) sacc += out[src * DIM + lane];
    }

    float* Rw = R + wave * 32 * 128;
    #pragma unroll
    for (int i = 0; i < 32; ++i) {
        Rw[i * 128 + lane]      = Racc[i];        // h = lane
        Rw[i * 128 + 64 + lane] = Racc[32 + i];   // h = lane+64
    }
    if (lane < DIM) Sg[n * DIM + lane] = sacc;
    __syncthreads();

    // contraction: thread -> (o = t>>3, c = t&7), c covers h-chunk [c*16, c*16+16)
    int o = t >> 3, c = t & 7;
    const float4* Wv = (const float4*)w2t + o * 1024 + c * 4;
    const float4* Rv = (const float4*)R;
    float acc0 = 0.f, acc1 = 0.f, acc2 = 0.f, acc3 = 0.f;
    for (int i = 0; i < 32; ++i) {
        int rb = i * 32 + c * 4;
        #pragma unroll
        for (int u = 0; u < 4; ++u) {
            float4 w  = Wv[i * 32 + u];
            float4 ra = Rv[0 * 1024 + rb + u];
            float4 rbv= Rv[1 * 1024 + rb + u];
            float4 rc = Rv[2 * 1024 + rb + u];
            float4 rd = Rv[3 * 1024 + rb + u];
            acc0 += ra.x  * w.x + ra.y  * w.y + ra.z  * w.z + ra.w  * w.w;
            acc1 += rbv.x * w.x + rbv.y * w.y + rbv.z * w.z + rbv.w * w.w;
            acc2 += rc.x  * w.x + rc.y  * w.y + rc.z  * w.z + rc.w  * w.w;
            acc3 += rd.x  * w.x + rd.y  * w.y + rd.z  * w.z + rd.w  * w.w;
        }
    }
    #pragma unroll
    for (int s = 1; s < 8; s <<= 1) {
        acc0 += __shfl_xor(acc0, s);
        acc1 += __shfl_xor(acc1, s);
        acc2 += __shfl_xor(acc2, s);
        acc3 += __shfl_xor(acc3, s);
    }
    if (c == 0) {
        float accs[4] = {acc0, acc1, acc2, acc3};
        #pragma unroll
        for (int nb = 0; nb < 4; ++nb) {
            int nn_ = n0 + nb;
            float bterm = 0.f;
            for (int i = 0; i < DIM; ++i) bterm += Sg[nn_ * DIM + i] * b2[i * DIM + o];
            agg[nn_ * DIM + o] = (accs[nb] + bterm) / deg[nn_];
        }
    }
}

// ---------------------------------------------------------------- GRU (+root)
__global__ __launch_bounds__(256) void k_gru(
    const float* __restrict__ agg, const float* __restrict__ root, const float* __restrict__ cbias,
    const float* __restrict__ wih, const float* __restrict__ whh,
    const float* __restrict__ bih, const float* __restrict__ bhh,
    float* __restrict__ out)
{
    __shared__ float so[8][33], sm[8][33];
    int t = threadIdx.x;
    int ln = t >> 5, d = t & 31;
    int n = blockIdx.x * 8 + ln;
    so[ln][d] = out[n * DIM + d];
    __syncthreads();
    float acc = agg[n * DIM + d] + cbias[d];
    for (int k = 0; k < DIM; ++k) acc += so[ln][k] * root[k * DIM + d];
    float m = fmaxf(acc, 0.f);
    sm[ln][d] = m;
    __syncthreads();
    float gir = bih[d], giz = bih[DIM + d], gin = bih[2 * DIM + d];
    float ghr = bhh[d], ghz = bhh[DIM + d], ghn = bhh[2 * DIM + d];
    for (int k = 0; k < DIM; ++k) {
        float mk = sm[ln][k], hk = so[ln][k];
        gir += mk * wih[k * 96 + d];
        giz += mk * wih[k * 96 + DIM + d];
        gin += mk * wih[k * 96 + 2 * DIM + d];
        ghr += hk * whh[k * 96 + d];
        ghz += hk * whh[k * 96 + DIM + d];
        ghn += hk * whh[k * 96 + 2 * DIM + d];
    }
    float rg = sigmoidf_(gir + ghr);
    float zg = sigmoidf_(giz + ghz);
    float ng = tanhf(gin + rg * ghn);
    float h_new = (1.f - zg) * ng + zg * so[ln][d];
    out[n * DIM + d] = h_new;
}

// ---------------------------------------------------------------- Set2Set
__global__ void k_lstm(const float* __restrict__ wih, const float* __restrict__ whh,
                       const float* __restrict__ bih, const float* __restrict__ bhh,
                       float* __restrict__ q_star, float* __restrict__ hh, float* __restrict__ cc)
{
    __shared__ float sq[NG][2 * DIM];
    __shared__ float sh[NG][DIM];
    __shared__ float sg[NG][4 * DIM];
    int t = threadIdx.x;
    for (int idx = t; idx < NG * 2 * DIM; idx += 256) sq[idx >> 6][idx & 63] = q_star[idx];
    for (int idx = t; idx < NG * DIM; idx += 256)     sh[idx >> 5][idx & 31] = hh[idx];
    __syncthreads();
    for (int idx = t; idx < NG * 4 * DIM; idx += 256) {
        int g = idx >> 7, j = idx & 127;
        float acc = bih[j] + bhh[j];
        for (int k = 0; k < 2 * DIM; ++k) acc += sq[g][k] * wih[k * 128 + j];
        for (int k = 0; k < DIM; ++k)     acc += sh[g][k] * whh[k * 128 + j];
        sg[g][j] = acc;
    }
    __syncthreads();
    for (int idx = t; idx < NG * DIM; idx += 256) {
        int g = idx >> 5, d = idx & 31;
        float ig = sigmoidf_(sg[g][d]);
        float fg = sigmoidf_(sg[g][DIM + d]);
        float gg = tanhf(sg[g][2 * DIM + d]);
        float og = sigmoidf_(sg[g][3 * DIM + d]);
        float c_new = fg * cc[idx] + ig * gg;
        float h_new = og * tanhf(c_new);
        cc[idx] = c_new;
        hh[idx] = h_new;
        q_star[g * 2 * DIM + d] = h_new;   // first half = q
    }
}

__global__ void k_attn(const float* __restrict__ out, const float* __restrict__ hh,
                       const int* __restrict__ gstart, float* __restrict__ ebuf,
                       float* __restrict__ q_star)
{
    int g = blockIdx.x, t = threadIdx.x;
    __shared__ float sq[DIM];
    __shared__ float srv[DIM];
    __shared__ float sred[256];
    if (t < DIM) { sq[t] = hh[g * DIM + t]; srv[t] = 0.f; }
    __syncthreads();
    int ns = gstart[g], neP = gstart[g + 1];

    float lmax = -1e30f;
    for (int n = ns + t; n < neP; n += 256) {
        const float* orow = out + n * DIM;
        float e = 0.f;
        for (int d = 0; d < DIM; ++d) e += orow[d] * sq[d];
        ebuf[n] = e;
        lmax = fmaxf(lmax, e);
    }
    sred[t] = lmax; __syncthreads();
    for (int s = 128; s > 0; s >>= 1) { if (t < s) sred[t] = fmaxf(sred[t], sred[t + s]); __syncthreads(); }
    float M = sred[0]; __syncthreads();

    float lsum = 0.f;
    for (int n = ns + t; n < neP; n += 256) {
        float v = expf(ebuf[n] - M);
        ebuf[n] = v;
        lsum += v;
    }
    sred[t] = lsum; __syncthreads();
    for (int s = 128; s > 0; s >>= 1) { if (t < s) sred[t] += sred[t + s]; __syncthreads(); }
    float S = sred[0];
    float inv = (S > 0.f) ? 1.f / S : 0.f;
    for (int n = ns + t; n < neP; n += 256) {
        float w = ebuf[n] * inv;
        const float* orow = out + n * DIM;
        for (int d = 0; d < DIM; ++d) atomicAdd(&srv[d], w * orow[d]);
    }
    __syncthreads();
    if (t < DIM) q_star[g * 2 * DIM + DIM + t] = srv[t];
}

__global__ void k_head(const float* __restrict__ q_star, const float* __restrict__ w1,
                       const float* __restrict__ b1, const float* __restrict__ w2,
                       const float* __restrict__ b2, float* __restrict__ y)
{
    int g = threadIdx.x;
    if (g >= NG) return;
    float q[64];
    for (int k = 0; k < 64; ++k) q[k] = q_star[g * 64 + k];
    float acc = b2[0];
    for (int j = 0; j < DIM; ++j) {
        float h = b1[j];
        for (int k = 0; k < 64; ++k) h += q[k] * w1[k * DIM + j];
        h = fmaxf(h, 0.f);
        acc += h * w2[j];
    }
    y[g] = acc;
}

// ---------------------------------------------------------------- launch
extern "C" void kernel_launch(void* const* d_in, const int* in_sizes, int n_in,
                              void* d_out, int out_size, void* d_ws, size_t ws_size,
                              hipStream_t stream) {
    const float* x         = (const float*)d_in[0];
    const float* edge_attr = (const float*)d_in[1];
    const float* lin0_w    = (const float*)d_in[2];
    const float* lin0_b    = (const float*)d_in[3];
    const float* nn_w1     = (const float*)d_in[4];
    const float* nn_b1     = (const float*)d_in[5];
    const float* nn_w2     = (const float*)d_in[6];
    const float* nn_b2     = (const float*)d_in[7];
    const float* conv_root = (const float*)d_in[8];
    const float* conv_bias = (const float*)d_in[9];
    const float* gru_w_ih  = (const float*)d_in[10];
    const float* gru_w_hh  = (const float*)d_in[11];
    const float* gru_b_ih  = (const float*)d_in[12];
    const float* gru_b_hh  = (const float*)d_in[13];
    const float* lstm_w_ih = (const float*)d_in[14];
    const float* lstm_w_hh = (const float*)d_in[15];
    const float* lstm_b_ih = (const float*)d_in[16];
    const float* lstm_b_hh = (const float*)d_in[17];
    const float* lin1_w    = (const float*)d_in[18];
    const float* lin1_b    = (const float*)d_in[19];
    const float* lin2_w    = (const float*)d_in[20];
    const float* lin2_b    = (const float*)d_in[21];
    const int*   edge_index= (const int*)d_in[22];
    const int*   batch     = (const int*)d_in[23];
    float* yout = (float*)d_out;

    char* p = (char*)d_ws;
    auto alloc = [&](size_t bytes) { char* r = p; p += (bytes + 255) & ~(size_t)255; return r; };

    // ---- zero region (one memset) ----
    int*   cnt    = (int*)  alloc(NN * sizeof(int));
    int*   cursor = (int*)  alloc(NN * sizeof(int));
    float* q_star = (float*)alloc(NG * 2 * DIM * sizeof(float));
    float* hh     = (float*)alloc(NG * DIM * sizeof(float));
    float* cc     = (float*)alloc(NG * DIM * sizeof(float));
    size_t zero_bytes = (size_t)(p - (char*)d_ws);
    // ---- rest ----
    int*   row_start = (int*)  alloc((NN + 1) * sizeof(int));
    int*   gstart    = (int*)  alloc((NG + 1) * sizeof(int));
    int*   eidx      = (int*)  alloc(NE * sizeof(int));
    float* deg       = (float*)alloc(NN * sizeof(float));
    float* out       = (float*)alloc(NN * DIM * sizeof(float));
    float* agg       = (float*)alloc(NN * DIM * sizeof(float));
    float* Sg        = (float*)alloc(NN * DIM * sizeof(float));
    float* w2t       = (float*)alloc(128 * 1024 * sizeof(float));
    float* ebuf      = (float*)alloc(NN * sizeof(float));
    (void)ws_size; (void)n_in; (void)in_sizes; (void)out_size;

    hipMemsetAsync(d_ws, 0, zero_bytes, stream);

    k_w2t   <<<512,  256, 0, stream>>>(nn_w2, w2t);
    k_count <<<625,  256, 0, stream>>>(edge_index, cnt);
    k_scan  <<<1,    256, 0, stream>>>(cnt, row_start, deg);
    k_fill  <<<625,  256, 0, stream>>>(edge_index, row_start, cursor, eidx);
    k_gstart<<<1,    128, 0, stream>>>(batch, gstart);
    k_lin0  <<<1250, 256, 0, stream>>>(x, lin0_w, lin0_b, out);

    for (int it = 0; it < 3; ++it) {
        k_conv<<<2500, 256, 0, stream>>>(row_start, eidx, edge_index, edge_attr,
                                         nn_w1, nn_b1, w2t, nn_b2, out, deg, Sg, agg);
        k_gru <<<1250, 256, 0, stream>>>(agg, conv_root, conv_bias,
                                         gru_w_ih, gru_w_hh, gru_b_ih, gru_b_hh, out);
    }
    for (int st = 0; st < 3; ++st) {
        k_lstm<<<1,  256, 0, stream>>>(lstm_w_ih, lstm_w_hh, lstm_b_ih, lstm_b_hh,
                                       q_star, hh, cc);
        k_attn<<<NG, 256, 0, stream>>>(out, hh, gstart, ebuf, q_star);
    }
    k_head<<<1, 64, 0, stream>>>(q_star, lin1_w, lin1_b, lin2_w, lin2_b, yout);
}

// Round 2
// 1070.374 us; speedup vs baseline: 1.1376x; 1.1376x over previous
//
#include <hip/hip_runtime.h>
#include <math.h>

#define NN 10000
#define NE 160000
#define NG 64
#define DIM 32

__device__ __forceinline__ float sigmoidf_(float x) { return 1.f / (1.f + expf(-x)); }

// ---------------------------------------------------------------- CSR build
__global__ void k_count(const int* __restrict__ ei, int* __restrict__ cnt) {
    int e = blockIdx.x * 256 + threadIdx.x;
    if (e < NE) atomicAdd(&cnt[ei[NE + e]], 1);
}

__global__ void k_scan(const int* __restrict__ cnt, int* __restrict__ row_start,
                       float* __restrict__ deg) {
    __shared__ int sums[256];
    int t = threadIdx.x;
    const int chunk = (NN + 255) / 256;   // 40
    int begin = t * chunk;
    int end = begin + chunk; if (end > NN) end = NN;
    int s = 0;
    for (int i = begin; i < end; ++i) s += cnt[i];
    sums[t] = s;
    __syncthreads();
    if (t == 0) {
        int acc = 0;
        for (int i = 0; i < 256; ++i) { int v = sums[i]; sums[i] = acc; acc += v; }
        row_start[NN] = acc;   // == NE
    }
    __syncthreads();
    int acc = sums[t];
    for (int i = begin; i < end; ++i) {
        row_start[i] = acc;
        int c = cnt[i];
        deg[i] = (float)(c > 0 ? c : 1);
        acc += c;
    }
}

// sort edge payloads by dst so the conv edge loop reads wave-uniform sequential data
__global__ void k_fill(const int* __restrict__ ei, const float* __restrict__ ea,
                       const int* __restrict__ row_start, int* __restrict__ cursor,
                       int* __restrict__ srt_src, float* __restrict__ srt_ea) {
    int e = blockIdx.x * 256 + threadIdx.x;
    if (e >= NE) return;
    int d = ei[NE + e];
    int p = atomicAdd(&cursor[d], 1);
    int pos = row_start[d] + p;
    srt_src[pos] = ei[e];
    srt_ea[2 * pos]     = ea[2 * e];
    srt_ea[2 * pos + 1] = ea[2 * e + 1];
}

__global__ void k_gstart(const int* __restrict__ batch, int* __restrict__ gstart) {
    int g = threadIdx.x;
    if (g > NG) return;
    int lo = 0, hi = NN;
    while (lo < hi) { int mid = (lo + hi) >> 1; if (batch[mid] < g) lo = mid + 1; else hi = mid; }
    gstart[g] = lo;
}

// W2 (128,1024) row-major [h][i*32+o]  ->  w2t [o][i][h]  (o*4096 + i*128 + h)
__global__ void k_w2t(const float* __restrict__ w2, float* __restrict__ w2t) {
    int idx = blockIdx.x * 256 + threadIdx.x;   // < 131072
    int h = idx >> 10, rem = idx & 1023, i = rem >> 5, o = rem & 31;
    w2t[o * 4096 + i * 128 + h] = w2[idx];
}

__global__ void k_lin0(const float* __restrict__ x, const float* __restrict__ w,
                       const float* __restrict__ b, float* __restrict__ out) {
    int idx = blockIdx.x * 256 + threadIdx.x;   // < NN*DIM
    int n = idx >> 5, d = idx & 31;
    out[idx] = fmaxf(x[n] * w[d] + b[d], 0.f);
}

// ---------------------------------------------------------------- NNConv + GRU fused
// Block: 4 nodes. Edge phase: wave per node, lane owns h=lane & h=lane+64 (R in 64 regs).
// Contraction: thread=(og=t>>5, c'=t&31); 4-node x 4-o register tile; R read as 32
// consecutive float4 per instr (conflict-free); W2 read coalesced 512B/og-half.
// Epilogue: GRU fused (shfl-based 32-dim matvecs), writes out_new.
__global__ __launch_bounds__(256, 2) void k_conv_gru(
    const int* __restrict__ row_start, const int* __restrict__ srt_src,
    const float* __restrict__ srt_ea,
    const float* __restrict__ w1, const float* __restrict__ b1,
    const float* __restrict__ w2t, const float* __restrict__ b2,
    const float* __restrict__ out_old, const float* __restrict__ deg,
    float* __restrict__ Sg,
    const float* __restrict__ root, const float* __restrict__ cbias,
    const float* __restrict__ wih, const float* __restrict__ whh,
    const float* __restrict__ bih, const float* __restrict__ bhh,
    float* __restrict__ out_new)
{
    __shared__ float R[4 * 32 * 128];   // [nb][i][h] = 64 KB
    int t = threadIdx.x;
    int wave = t >> 6, lane = t & 63;
    int n0 = blockIdx.x * 4;
    int n = n0 + wave;

    // ---------------- edge phase ----------------
    float Racc[64];
    #pragma unroll
    for (int i = 0; i < 64; ++i) Racc[i] = 0.f;
    float sacc = 0.f;

    float w1a0 = w1[lane],      w1c0 = w1[128 + lane],  bb0 = b1[lane];
    float w1a1 = w1[64 + lane], w1c1 = w1[192 + lane],  bb1 = b1[64 + lane];

    int rs = row_start[n], re = row_start[n + 1];
    for (int p = rs; p < re; ++p) {
        int src = srt_src[p];                       // wave-uniform
        float a0 = srt_ea[2 * p], a1 = srt_ea[2 * p + 1];
        float r0 = fmaxf(a0 * w1a0 + a1 * w1c0 + bb0, 0.f);
        float r1 = fmaxf(a0 * w1a1 + a1 * w1c1 + bb1, 0.f);
        const float4* op = (const float4*)(out_old + src * DIM);
        #pragma unroll
        for (int q = 0; q < 8; ++q) {
            float4 o4 = op[q];
            Racc[4 * q + 0]      += r0 * o4.x;
            Racc[4 * q + 1]      += r0 * o4.y;
            Racc[4 * q + 2]      += r0 * o4.z;
            Racc[4 * q + 3]      += r0 * o4.w;
            Racc[32 + 4 * q + 0] += r1 * o4.x;
            Racc[32 + 4 * q + 1] += r1 * o4.y;
            Racc[32 + 4 * q + 2] += r1 * o4.z;
            Racc[32 + 4 * q + 3] += r1 * o4.w;
        }
        if (lane < DIM) sacc += out_old[src * DIM + lane];
    }

    float* Rw = R + wave * 32 * 128;
    #pragma unroll
    for (int i = 0; i < 32; ++i) {
        Rw[i * 128 + lane]      = Racc[i];        // h = lane       (2-way = free)
        Rw[i * 128 + 64 + lane] = Racc[32 + i];   // h = lane+64
    }
    if (lane < DIM) Sg[n * DIM + lane] = sacc;
    __syncthreads();

    // ---------------- contraction ----------------
    int og = t >> 5, cp = t & 31;                  // o-tile = og*4..+3, h-float4 = cp
    float acc[4][4];
    #pragma unroll
    for (int a = 0; a < 4; ++a)
        #pragma unroll
        for (int b = 0; b < 4; ++b) acc[a][b] = 0.f;

    const float4* Rv = (const float4*)R;
    const float4* Wv = (const float4*)w2t;
    #pragma unroll 2
    for (int i = 0; i < 32; ++i) {
        int rb = i * 32 + cp;
        float4 r0 = Rv[rb];
        float4 r1 = Rv[1024 + rb];
        float4 r2 = Rv[2048 + rb];
        float4 r3 = Rv[3072 + rb];
        #pragma unroll
        for (int ot = 0; ot < 4; ++ot) {
            float4 w = Wv[(og * 4 + ot) * 1024 + i * 32 + cp];
            acc[0][ot] += r0.x * w.x + r0.y * w.y + r0.z * w.z + r0.w * w.w;
            acc[1][ot] += r1.x * w.x + r1.y * w.y + r1.z * w.z + r1.w * w.w;
            acc[2][ot] += r2.x * w.x + r2.y * w.y + r2.z * w.z + r2.w * w.w;
            acc[3][ot] += r3.x * w.x + r3.y * w.y + r3.z * w.z + r3.w * w.w;
        }
    }
    #pragma unroll
    for (int s = 1; s < 32; s <<= 1) {
        #pragma unroll
        for (int nb = 0; nb < 4; ++nb)
            #pragma unroll
            for (int ot = 0; ot < 4; ++ot)
                acc[nb][ot] += __shfl_xor(acc[nb][ot], s);
    }
    __syncthreads();                               // all R reads complete
    if (cp == 0) {                                 // stash agg into R[0..127]
        #pragma unroll
        for (int nb = 0; nb < 4; ++nb)
            #pragma unroll
            for (int ot = 0; ot < 4; ++ot)
                R[nb * 32 + og * 4 + ot] = acc[nb][ot];
    }
    __syncthreads();

    // ---------------- fused GRU epilogue (threads 0..127) ----------------
    if (t < 128) {
        int nb = t >> 5, d = t & 31, nn_ = n0 + nb;
        int base = t & 32;                          // shfl base within wave
        float aggv = R[nb * 32 + d];
        float bt = 0.f;
        #pragma unroll 8
        for (int i = 0; i < DIM; ++i) bt += Sg[nn_ * DIM + i] * b2[i * DIM + d];
        aggv = (aggv + bt) / deg[nn_];

        float x = out_old[nn_ * DIM + d];           // h_old[d]
        float rootsum = 0.f;
        #pragma unroll 8
        for (int k = 0; k < DIM; ++k)
            rootsum += __shfl(x, base + k) * root[k * DIM + d];
        float m = fmaxf(aggv + rootsum + cbias[d], 0.f);

        float gir = bih[d], giz = bih[DIM + d], gin = bih[2 * DIM + d];
        float ghr = bhh[d], ghz = bhh[DIM + d], ghn = bhh[2 * DIM + d];
        #pragma unroll 4
        for (int k = 0; k < DIM; ++k) {
            float mk = __shfl(m, base + k);
            float hk = __shfl(x, base + k);
            gir += mk * wih[k * 96 + d];
            giz += mk * wih[k * 96 + DIM + d];
            gin += mk * wih[k * 96 + 2 * DIM + d];
            ghr += hk * whh[k * 96 + d];
            ghz += hk * whh[k * 96 + DIM + d];
            ghn += hk * whh[k * 96 + 2 * DIM + d];
        }
        float rg = sigmoidf_(gir + ghr);
        float zg = sigmoidf_(giz + ghz);
        float ng = tanhf(gin + rg * ghn);
        out_new[nn_ * DIM + d] = (1.f - zg) * ng + zg * x;
    }
}

// ---------------------------------------------------------------- Set2Set
__global__ void k_lstm(const float* __restrict__ wih, const float* __restrict__ whh,
                       const float* __restrict__ bih, const float* __restrict__ bhh,
                       float* __restrict__ q_star, float* __restrict__ hh, float* __restrict__ cc)
{
    __shared__ float sq[NG][2 * DIM];
    __shared__ float sh[NG][DIM];
    __shared__ float sg[NG][4 * DIM];
    int t = threadIdx.x;
    for (int idx = t; idx < NG * 2 * DIM; idx += 256) sq[idx >> 6][idx & 63] = q_star[idx];
    for (int idx = t; idx < NG * DIM; idx += 256)     sh[idx >> 5][idx & 31] = hh[idx];
    __syncthreads();
    for (int idx = t; idx < NG * 4 * DIM; idx += 256) {
        int g = idx >> 7, j = idx & 127;
        float acc = bih[j] + bhh[j];
        for (int k = 0; k < 2 * DIM; ++k) acc += sq[g][k] * wih[k * 128 + j];
        for (int k = 0; k < DIM; ++k)     acc += sh[g][k] * whh[k * 128 + j];
        sg[g][j] = acc;
    }
    __syncthreads();
    for (int idx = t; idx < NG * DIM; idx += 256) {
        int g = idx >> 5, d = idx & 31;
        float ig = sigmoidf_(sg[g][d]);
        float fg = sigmoidf_(sg[g][DIM + d]);
        float gg = tanhf(sg[g][2 * DIM + d]);
        float og = sigmoidf_(sg[g][3 * DIM + d]);
        float c_new = fg * cc[idx] + ig * gg;
        float h_new = og * tanhf(c_new);
        cc[idx] = c_new;
        hh[idx] = h_new;
        q_star[g * 2 * DIM + d] = h_new;   // first half = q
    }
}

__global__ void k_attn(const float* __restrict__ out, const float* __restrict__ hh,
                       const int* __restrict__ gstart, float* __restrict__ ebuf,
                       float* __restrict__ q_star)
{
    int g = blockIdx.x, t = threadIdx.x;
    __shared__ float sq[DIM];
    __shared__ float srv[DIM];
    __shared__ float sred[256];
    if (t < DIM) { sq[t] = hh[g * DIM + t]; srv[t] = 0.f; }
    __syncthreads();
    int ns = gstart[g], neP = gstart[g + 1];

    float lmax = -1e30f;
    for (int n = ns + t; n < neP; n += 256) {
        const float* orow = out + n * DIM;
        float e = 0.f;
        for (int d = 0; d < DIM; ++d) e += orow[d] * sq[d];
        ebuf[n] = e;
        lmax = fmaxf(lmax, e);
    }
    sred[t] = lmax; __syncthreads();
    for (int s = 128; s > 0; s >>= 1) { if (t < s) sred[t] = fmaxf(sred[t], sred[t + s]); __syncthreads(); }
    float M = sred[0]; __syncthreads();

    float lsum = 0.f;
    for (int n = ns + t; n < neP; n += 256) {
        float v = expf(ebuf[n] - M);
        ebuf[n] = v;
        lsum += v;
    }
    sred[t] = lsum; __syncthreads();
    for (int s = 128; s > 0; s >>= 1) { if (t < s) sred[t] += sred[t + s]; __syncthreads(); }
    float S = sred[0];
    float inv = (S > 0.f) ? 1.f / S : 0.f;
    for (int n = ns + t; n < neP; n += 256) {
        float w = ebuf[n] * inv;
        const float* orow = out + n * DIM;
        for (int d = 0; d < DIM; ++d) atomicAdd(&srv[d], w * orow[d]);
    }
    __syncthreads();
    if (t < DIM) q_star[g * 2 * DIM + DIM + t] = srv[t];
}

__global__ void k_head(const float* __restrict__ q_star, const float* __restrict__ w1,
                       const float* __restrict__ b1, const float* __restrict__ w2,
                       const float* __restrict__ b2, float* __restrict__ y)
{
    int g = threadIdx.x;
    if (g >= NG) return;
    float q[64];
    for (int k = 0; k < 64; ++k) q[k] = q_star[g * 64 + k];
    float acc = b2[0];
    for (int j = 0; j < DIM; ++j) {
        float h = b1[j];
        for (int k = 0; k < 64; ++k) h += q[k] * w1[k * DIM + j];
        h = fmaxf(h, 0.f);
        acc += h * w2[j];
    }
    y[g] = acc;
}

// ---------------------------------------------------------------- launch
extern "C" void kernel_launch(void* const* d_in, const int* in_sizes, int n_in,
                              void* d_out, int out_size, void* d_ws, size_t ws_size,
                              hipStream_t stream) {
    const float* x         = (const float*)d_in[0];
    const float* edge_attr = (const float*)d_in[1];
    const float* lin0_w    = (const float*)d_in[2];
    const float* lin0_b    = (const float*)d_in[3];
    const float* nn_w1     = (const float*)d_in[4];
    const float* nn_b1     = (const float*)d_in[5];
    const float* nn_w2     = (const float*)d_in[6];
    const float* nn_b2     = (const float*)d_in[7];
    const float* conv_root = (const float*)d_in[8];
    const float* conv_bias = (const float*)d_in[9];
    const float* gru_w_ih  = (const float*)d_in[10];
    const float* gru_w_hh  = (const float*)d_in[11];
    const float* gru_b_ih  = (const float*)d_in[12];
    const float* gru_b_hh  = (const float*)d_in[13];
    const float* lstm_w_ih = (const float*)d_in[14];
    const float* lstm_w_hh = (const float*)d_in[15];
    const float* lstm_b_ih = (const float*)d_in[16];
    const float* lstm_b_hh = (const float*)d_in[17];
    const float* lin1_w    = (const float*)d_in[18];
    const float* lin1_b    = (const float*)d_in[19];
    const float* lin2_w    = (const float*)d_in[20];
    const float* lin2_b    = (const float*)d_in[21];
    const int*   edge_index= (const int*)d_in[22];
    const int*   batch     = (const int*)d_in[23];
    float* yout = (float*)d_out;

    char* p = (char*)d_ws;
    auto alloc = [&](size_t bytes) { char* r = p; p += (bytes + 255) & ~(size_t)255; return r; };

    // ---- zero region (one memset) ----
    int*   cnt    = (int*)  alloc(NN * sizeof(int));
    int*   cursor = (int*)  alloc(NN * sizeof(int));
    float* q_star = (float*)alloc(NG * 2 * DIM * sizeof(float));
    float* hh     = (float*)alloc(NG * DIM * sizeof(float));
    float* cc     = (float*)alloc(NG * DIM * sizeof(float));
    size_t zero_bytes = (size_t)(p - (char*)d_ws);
    // ---- rest ----
    int*   row_start = (int*)  alloc((NN + 1) * sizeof(int));
    int*   gstart    = (int*)  alloc((NG + 1) * sizeof(int));
    int*   srt_src   = (int*)  alloc(NE * sizeof(int));
    float* srt_ea    = (float*)alloc(2 * NE * sizeof(float));
    float* deg       = (float*)alloc(NN * sizeof(float));
    float* outA      = (float*)alloc(NN * DIM * sizeof(float));
    float* outB      = (float*)alloc(NN * DIM * sizeof(float));
    float* Sg        = (float*)alloc(NN * DIM * sizeof(float));
    float* w2t       = (float*)alloc(128 * 1024 * sizeof(float));
    float* ebuf      = (float*)alloc(NN * sizeof(float));
    (void)ws_size; (void)n_in; (void)in_sizes; (void)out_size;

    hipMemsetAsync(d_ws, 0, zero_bytes, stream);

    k_w2t   <<<512,  256, 0, stream>>>(nn_w2, w2t);
    k_count <<<625,  256, 0, stream>>>(edge_index, cnt);
    k_scan  <<<1,    256, 0, stream>>>(cnt, row_start, deg);
    k_fill  <<<625,  256, 0, stream>>>(edge_index, edge_attr, row_start, cursor, srt_src, srt_ea);
    k_gstart<<<1,    128, 0, stream>>>(batch, gstart);
    k_lin0  <<<1250, 256, 0, stream>>>(x, lin0_w, lin0_b, outA);

    const float* cur = outA;
    float* nxt = outB;
    for (int it = 0; it < 3; ++it) {
        k_conv_gru<<<2500, 256, 0, stream>>>(row_start, srt_src, srt_ea,
                                             nn_w1, nn_b1, w2t, nn_b2,
                                             cur, deg, Sg,
                                             conv_root, conv_bias,
                                             gru_w_ih, gru_w_hh, gru_b_ih, gru_b_hh,
                                             nxt);
        const float* tmp = nxt; nxt = (float*)cur; cur = tmp;
    }
    const float* outF = cur;   // after 3 iters: outB

    for (int st = 0; st < 3; ++st) {
        k_lstm<<<1,  256, 0, stream>>>(lstm_w_ih, lstm_w_hh, lstm_b_ih, lstm_b_hh,
                                       q_star, hh, cc);
        k_attn<<<NG, 256, 0, stream>>>(outF, hh, gstart, ebuf, q_star);
    }
    k_head<<<1, 64, 0, stream>>>(q_star, lin1_w, lin1_b, lin2_w, lin2_b, yout);
}

// Round 3
// 734.391 us; speedup vs baseline: 1.6581x; 1.4575x over previous
//
#include <hip/hip_runtime.h>
#include <math.h>

#define NN 10000
#define NE 160000
#define NG 64
#define DIM 32

__device__ __forceinline__ float sigmoidf_(float x) { return 1.f / (1.f + expf(-x)); }

// ---------------------------------------------------------------- fused setup
// roles by blockIdx.x:
//   [0,512)        : w2t transpose  (128x1024 -> [o][i][h])
//   [512,1137)     : count dst degrees (cnt pre-zeroed by memset)
//   [1137,2387)    : lin0 + relu
//   2387           : gstart binary search
__global__ void k_setup(const float* __restrict__ w2, float* __restrict__ w2t,
                        const int* __restrict__ ei, int* __restrict__ cnt,
                        const float* __restrict__ x, const float* __restrict__ lw,
                        const float* __restrict__ lb, float* __restrict__ out,
                        const int* __restrict__ batch, int* __restrict__ gstart) {
    int b = blockIdx.x, t = threadIdx.x;
    if (b < 512) {
        int idx = b * 256 + t;                       // < 131072
        int h = idx >> 10, rem = idx & 1023, i = rem >> 5, o = rem & 31;
        w2t[o * 4096 + i * 128 + h] = w2[idx];
    } else if (b < 1137) {
        int e = (b - 512) * 256 + t;
        if (e < NE) atomicAdd(&cnt[ei[NE + e]], 1);
    } else if (b < 2387) {
        int idx = (b - 1137) * 256 + t;              // < NN*DIM
        int n = idx >> 5, d = idx & 31;
        out[idx] = fmaxf(x[n] * lw[d] + lb[d], 0.f);
    } else {
        if (t <= NG) {
            int g = t, lo = 0, hi = NN;
            while (lo < hi) { int mid = (lo + hi) >> 1; if (batch[mid] < g) lo = mid + 1; else hi = mid; }
            gstart[g] = lo;
        }
    }
}

__global__ void k_scan(const int* __restrict__ cnt, int* __restrict__ row_start,
                       float* __restrict__ deg) {
    __shared__ int sums[256];
    int t = threadIdx.x;
    const int chunk = (NN + 255) / 256;   // 40
    int begin = t * chunk;
    int end = begin + chunk; if (end > NN) end = NN;
    int s = 0;
    for (int i = begin; i < end; ++i) s += cnt[i];
    sums[t] = s;
    __syncthreads();
    if (t == 0) {
        int acc = 0;
        for (int i = 0; i < 256; ++i) { int v = sums[i]; sums[i] = acc; acc += v; }
        row_start[NN] = acc;   // == NE
    }
    __syncthreads();
    int acc = sums[t];
    for (int i = begin; i < end; ++i) {
        row_start[i] = acc;
        int c = cnt[i];
        deg[i] = (float)(c > 0 ? c : 1);
        acc += c;
    }
}

// sort edge payloads by dst so the conv edge loop reads wave-uniform sequential data
__global__ void k_fill(const int* __restrict__ ei, const float* __restrict__ ea,
                       const int* __restrict__ row_start, int* __restrict__ cursor,
                       int* __restrict__ srt_src, float* __restrict__ srt_ea) {
    int e = blockIdx.x * 256 + threadIdx.x;
    if (e >= NE) return;
    int d = ei[NE + e];
    int p = atomicAdd(&cursor[d], 1);
    int pos = row_start[d] + p;
    srt_src[pos] = ei[e];
    srt_ea[2 * pos]     = ea[2 * e];
    srt_ea[2 * pos + 1] = ea[2 * e + 1];
}

// ---------------------------------------------------------------- NNConv + GRU fused
// Block: 4 nodes, one wave each. Edge phase: lane owns h=lane,h=lane+64; R in 64 regs.
// Contraction split over two i-halves so LDS = 32 KB (4-5 blocks/CU instead of 2).
__global__ __launch_bounds__(256, 4) void k_conv_gru(
    const int* __restrict__ row_start, const int* __restrict__ srt_src,
    const float* __restrict__ srt_ea,
    const float* __restrict__ w1, const float* __restrict__ b1,
    const float* __restrict__ w2t, const float* __restrict__ b2,
    const float* __restrict__ out_old, const float* __restrict__ deg,
    float* __restrict__ Sg,
    const float* __restrict__ root, const float* __restrict__ cbias,
    const float* __restrict__ wih, const float* __restrict__ whh,
    const float* __restrict__ bih, const float* __restrict__ bhh,
    float* __restrict__ out_new)
{
    __shared__ float R[4 * 16 * 128];   // [nb][i_half][h] = 32 KB
    int t = threadIdx.x;
    int wave = t >> 6, lane = t & 63;
    int n0 = blockIdx.x * 4;
    int n = n0 + wave;

    // ---------------- edge phase ----------------
    float Racc[64];
    #pragma unroll
    for (int i = 0; i < 64; ++i) Racc[i] = 0.f;
    float sacc = 0.f;

    float w1a0 = w1[lane],      w1c0 = w1[128 + lane],  bb0 = b1[lane];
    float w1a1 = w1[64 + lane], w1c1 = w1[192 + lane],  bb1 = b1[64 + lane];

    int rs = row_start[n], re = row_start[n + 1];
    const float2* eap = (const float2*)srt_ea;
    for (int p = rs; p < re; ++p) {
        int src = srt_src[p];                       // wave-uniform
        float2 a = eap[p];
        float r0 = fmaxf(a.x * w1a0 + a.y * w1c0 + bb0, 0.f);
        float r1 = fmaxf(a.x * w1a1 + a.y * w1c1 + bb1, 0.f);
        const float4* op = (const float4*)(out_old + src * DIM);
        #pragma unroll
        for (int q = 0; q < 8; ++q) {
            float4 o4 = op[q];
            Racc[4 * q + 0]      += r0 * o4.x;
            Racc[4 * q + 1]      += r0 * o4.y;
            Racc[4 * q + 2]      += r0 * o4.z;
            Racc[4 * q + 3]      += r0 * o4.w;
            Racc[32 + 4 * q + 0] += r1 * o4.x;
            Racc[32 + 4 * q + 1] += r1 * o4.y;
            Racc[32 + 4 * q + 2] += r1 * o4.z;
            Racc[32 + 4 * q + 3] += r1 * o4.w;
        }
        if (lane < DIM) sacc += out_old[src * DIM + lane];
    }
    if (lane < DIM) Sg[n * DIM + lane] = sacc;

    // ---------------- contraction (two i-halves) ----------------
    int og = t >> 5, cp = t & 31;                  // o-tile og*4..+3, h-float4 cp
    float acc[4][4];
    #pragma unroll
    for (int a = 0; a < 4; ++a)
        #pragma unroll
        for (int b = 0; b < 4; ++b) acc[a][b] = 0.f;

    float* Rw = R + wave * 16 * 128;
    const float4* Rv = (const float4*)R;
    const float4* Wv = (const float4*)w2t;

    #pragma unroll
    for (int half = 0; half < 2; ++half) {
        if (half) __syncthreads();                 // prior half's reads done
        #pragma unroll
        for (int q = half * 4; q < half * 4 + 4; ++q) {
            #pragma unroll
            for (int j = 0; j < 4; ++j) {
                int li = 4 * q + j - half * 16;    // 0..15
                Rw[li * 128 + lane]      = Racc[4 * q + j];        // h=lane (2-way free)
                Rw[li * 128 + 64 + lane] = Racc[32 + 4 * q + j];   // h=lane+64
            }
        }
        __syncthreads();
        #pragma unroll 2
        for (int i = 0; i < 16; ++i) {
            int rb = i * 32 + cp;
            float4 r0 = Rv[rb];
            float4 r1 = Rv[512 + rb];
            float4 r2 = Rv[1024 + rb];
            float4 r3 = Rv[1536 + rb];
            int gi = half * 16 + i;
            #pragma unroll
            for (int ot = 0; ot < 4; ++ot) {
                float4 w = Wv[(og * 4 + ot) * 1024 + gi * 32 + cp];
                acc[0][ot] += r0.x * w.x + r0.y * w.y + r0.z * w.z + r0.w * w.w;
                acc[1][ot] += r1.x * w.x + r1.y * w.y + r1.z * w.z + r1.w * w.w;
                acc[2][ot] += r2.x * w.x + r2.y * w.y + r2.z * w.z + r2.w * w.w;
                acc[3][ot] += r3.x * w.x + r3.y * w.y + r3.z * w.z + r3.w * w.w;
            }
        }
    }
    #pragma unroll
    for (int s = 1; s < 32; s <<= 1) {
        #pragma unroll
        for (int nb = 0; nb < 4; ++nb)
            #pragma unroll
            for (int ot = 0; ot < 4; ++ot)
                acc[nb][ot] += __shfl_xor(acc[nb][ot], s);
    }
    __syncthreads();                               // all R reads complete
    if (cp == 0) {                                 // stash agg into R[0..127]
        #pragma unroll
        for (int nb = 0; nb < 4; ++nb)
            #pragma unroll
            for (int ot = 0; ot < 4; ++ot)
                R[nb * 32 + og * 4 + ot] = acc[nb][ot];
    }
    __syncthreads();

    // ---------------- fused GRU epilogue (threads 0..127) ----------------
    if (t < 128) {
        int nb = t >> 5, d = t & 31, nn_ = n0 + nb;
        int base = t & 32;                          // shfl base within wave
        float aggv = R[nb * 32 + d];
        float bt = 0.f;
        #pragma unroll 8
        for (int i = 0; i < DIM; ++i) bt += Sg[nn_ * DIM + i] * b2[i * DIM + d];
        aggv = (aggv + bt) / deg[nn_];

        float x = out_old[nn_ * DIM + d];           // h_old[d]
        float rootsum = 0.f;
        #pragma unroll 8
        for (int k = 0; k < DIM; ++k)
            rootsum += __shfl(x, base + k) * root[k * DIM + d];
        float m = fmaxf(aggv + rootsum + cbias[d], 0.f);

        float gir = bih[d], giz = bih[DIM + d], gin = bih[2 * DIM + d];
        float ghr = bhh[d], ghz = bhh[DIM + d], ghn = bhh[2 * DIM + d];
        #pragma unroll 4
        for (int k = 0; k < DIM; ++k) {
            float mk = __shfl(m, base + k);
            float hk = __shfl(x, base + k);
            gir += mk * wih[k * 96 + d];
            giz += mk * wih[k * 96 + DIM + d];
            gin += mk * wih[k * 96 + 2 * DIM + d];
            ghr += hk * whh[k * 96 + d];
            ghz += hk * whh[k * 96 + DIM + d];
            ghn += hk * whh[k * 96 + 2 * DIM + d];
        }
        float rg = sigmoidf_(gir + ghr);
        float zg = sigmoidf_(giz + ghz);
        float ng = tanhf(gin + rg * ghn);
        out_new[nn_ * DIM + d] = (1.f - zg) * ng + zg * x;
    }
}

// ---------------------------------------------------------------- Set2Set + head, fused
// One block per graph; 3 LSTM+attention steps entirely in LDS, then the output head.
__global__ __launch_bounds__(256) void k_set2set(
    const float* __restrict__ out, const int* __restrict__ gstart,
    const float* __restrict__ wih, const float* __restrict__ whh,
    const float* __restrict__ bih, const float* __restrict__ bhh,
    const float* __restrict__ l1w, const float* __restrict__ l1b,
    const float* __restrict__ l2w, const float* __restrict__ l2b,
    float* __restrict__ ebuf, float* __restrict__ y)
{
    int g = blockIdx.x, t = threadIdx.x;
    __shared__ float sq[2 * DIM];    // q_star
    __shared__ float shh[DIM], scc[DIM];
    __shared__ float sg[4 * DIM];
    __shared__ float srv[DIM];
    __shared__ float sred[256];
    if (t < 2 * DIM) sq[t] = 0.f;
    if (t < DIM) { shh[t] = 0.f; scc[t] = 0.f; }
    int ns = gstart[g], ne = gstart[g + 1];

    for (int step = 0; step < 3; ++step) {
        __syncthreads();
        // LSTM gates
        if (t < 128) {
            float acc = bih[t] + bhh[t];
            for (int k = 0; k < 2 * DIM; ++k) acc += sq[k] * wih[k * 128 + t];
            for (int k = 0; k < DIM; ++k)     acc += shh[k] * whh[k * 128 + t];
            sg[t] = acc;
        }
        __syncthreads();
        if (t < DIM) {
            float ig = sigmoidf_(sg[t]);
            float fg = sigmoidf_(sg[DIM + t]);
            float gg = tanhf(sg[2 * DIM + t]);
            float og = sigmoidf_(sg[3 * DIM + t]);
            float c_new = fg * scc[t] + ig * gg;
            float h_new = og * tanhf(c_new);
            scc[t] = c_new;
            shh[t] = h_new;
            sq[t] = h_new;
            srv[t] = 0.f;
        }
        __syncthreads();
        // attention over this graph's nodes
        float lmax = -1e30f;
        for (int n = ns + t; n < ne; n += 256) {
            const float4* orow = (const float4*)(out + n * DIM);
            float e = 0.f;
            #pragma unroll
            for (int q = 0; q < 8; ++q) {
                float4 o4 = orow[q];
                e += o4.x * shh[4 * q] + o4.y * shh[4 * q + 1]
                   + o4.z * shh[4 * q + 2] + o4.w * shh[4 * q + 3];
            }
            ebuf[n] = e;
            lmax = fmaxf(lmax, e);
        }
        sred[t] = lmax; __syncthreads();
        for (int s = 128; s > 0; s >>= 1) { if (t < s) sred[t] = fmaxf(sred[t], sred[t + s]); __syncthreads(); }
        float M = sred[0]; __syncthreads();

        float lsum = 0.f;
        for (int n = ns + t; n < ne; n += 256) {
            float v = expf(ebuf[n] - M);
            ebuf[n] = v;
            lsum += v;
        }
        sred[t] = lsum; __syncthreads();
        for (int s = 128; s > 0; s >>= 1) { if (t < s) sred[t] += sred[t + s]; __syncthreads(); }
        float S = sred[0];
        float inv = (S > 0.f) ? 1.f / S : 0.f;
        for (int n = ns + t; n < ne; n += 256) {
            float w = ebuf[n] * inv;
            const float* orow = out + n * DIM;
            for (int d = 0; d < DIM; ++d) atomicAdd(&srv[d], w * orow[d]);
        }
        __syncthreads();
        if (t < DIM) sq[DIM + t] = srv[t];
    }
    __syncthreads();
    // head: y[g] = relu(q_star @ l1w + l1b) @ l2w + l2b
    if (t < DIM) {
        float h = l1b[t];
        for (int k = 0; k < 2 * DIM; ++k) h += sq[k] * l1w[k * DIM + t];
        float v = fmaxf(h, 0.f) * l2w[t];
        #pragma unroll
        for (int s = 1; s < 32; s <<= 1) v += __shfl_xor(v, s);
        if (t == 0) y[g] = v + l2b[0];
    }
}

// ---------------------------------------------------------------- launch
extern "C" void kernel_launch(void* const* d_in, const int* in_sizes, int n_in,
                              void* d_out, int out_size, void* d_ws, size_t ws_size,
                              hipStream_t stream) {
    const float* x         = (const float*)d_in[0];
    const float* edge_attr = (const float*)d_in[1];
    const float* lin0_w    = (const float*)d_in[2];
    const float* lin0_b    = (const float*)d_in[3];
    const float* nn_w1     = (const float*)d_in[4];
    const float* nn_b1     = (const float*)d_in[5];
    const float* nn_w2     = (const float*)d_in[6];
    const float* nn_b2     = (const float*)d_in[7];
    const float* conv_root = (const float*)d_in[8];
    const float* conv_bias = (const float*)d_in[9];
    const float* gru_w_ih  = (const float*)d_in[10];
    const float* gru_w_hh  = (const float*)d_in[11];
    const float* gru_b_ih  = (const float*)d_in[12];
    const float* gru_b_hh  = (const float*)d_in[13];
    const float* lstm_w_ih = (const float*)d_in[14];
    const float* lstm_w_hh = (const float*)d_in[15];
    const float* lstm_b_ih = (const float*)d_in[16];
    const float* lstm_b_hh = (const float*)d_in[17];
    const float* lin1_w    = (const float*)d_in[18];
    const float* lin1_b    = (const float*)d_in[19];
    const float* lin2_w    = (const float*)d_in[20];
    const float* lin2_b    = (const float*)d_in[21];
    const int*   edge_index= (const int*)d_in[22];
    const int*   batch     = (const int*)d_in[23];
    float* yout = (float*)d_out;

    char* p = (char*)d_ws;
    auto alloc = [&](size_t bytes) { char* r = p; p += (bytes + 255) & ~(size_t)255; return r; };

    // ---- zero region (one memset) ----
    int*   cnt    = (int*)  alloc(NN * sizeof(int));
    int*   cursor = (int*)  alloc(NN * sizeof(int));
    size_t zero_bytes = (size_t)(p - (char*)d_ws);
    // ---- rest ----
    int*   row_start = (int*)  alloc((NN + 1) * sizeof(int));
    int*   gstart    = (int*)  alloc((NG + 1) * sizeof(int));
    int*   srt_src   = (int*)  alloc(NE * sizeof(int));
    float* srt_ea    = (float*)alloc(2 * NE * sizeof(float));
    float* deg       = (float*)alloc(NN * sizeof(float));
    float* outA      = (float*)alloc(NN * DIM * sizeof(float));
    float* outB      = (float*)alloc(NN * DIM * sizeof(float));
    float* Sg        = (float*)alloc(NN * DIM * sizeof(float));
    float* w2t       = (float*)alloc(128 * 1024 * sizeof(float));
    float* ebuf      = (float*)alloc(NN * sizeof(float));
    (void)ws_size; (void)n_in; (void)in_sizes; (void)out_size;

    hipMemsetAsync(d_ws, 0, zero_bytes, stream);

    k_setup<<<2388, 256, 0, stream>>>(nn_w2, w2t, edge_index, cnt,
                                      x, lin0_w, lin0_b, outA, batch, gstart);
    k_scan <<<1,    256, 0, stream>>>(cnt, row_start, deg);
    k_fill <<<625,  256, 0, stream>>>(edge_index, edge_attr, row_start, cursor, srt_src, srt_ea);

    const float* cur = outA;
    float* nxt = outB;
    for (int it = 0; it < 3; ++it) {
        k_conv_gru<<<2500, 256, 0, stream>>>(row_start, srt_src, srt_ea,
                                             nn_w1, nn_b1, w2t, nn_b2,
                                             cur, deg, Sg,
                                             conv_root, conv_bias,
                                             gru_w_ih, gru_w_hh, gru_b_ih, gru_b_hh,
                                             nxt);
        const float* tmp = nxt; nxt = (float*)cur; cur = tmp;
    }
    const float* outF = cur;

    k_set2set<<<NG, 256, 0, stream>>>(outF, gstart,
                                      lstm_w_ih, lstm_w_hh, lstm_b_ih, lstm_b_hh,
                                      lin1_w, lin1_b, lin2_w, lin2_b, ebuf, yout);
}

// Round 4
// 532.838 us; speedup vs baseline: 2.2853x; 1.3783x over previous
//
#include <hip/hip_runtime.h>
#include <math.h>

#define NN 10000
#define NE 160000
#define NG 64
#define DIM 32

__device__ __forceinline__ float sigmoidf_(float x) { return 1.f / (1.f + expf(-x)); }

// ---------------------------------------------------------------- fused setup
// roles by blockIdx.x:
//   [0,512)        : w2t transpose  (128x1024 -> [o][i][h])
//   [512,1137)     : count dst degrees (cnt pre-zeroed by memset)
//   [1137,2387)    : lin0 + relu
//   2387           : gstart binary search
__global__ void k_setup(const float* __restrict__ w2, float* __restrict__ w2t,
                        const int* __restrict__ ei, int* __restrict__ cnt,
                        const float* __restrict__ x, const float* __restrict__ lw,
                        const float* __restrict__ lb, float* __restrict__ out,
                        const int* __restrict__ batch, int* __restrict__ gstart) {
    int b = blockIdx.x, t = threadIdx.x;
    if (b < 512) {
        int idx = b * 256 + t;                       // < 131072
        int h = idx >> 10, rem = idx & 1023, i = rem >> 5, o = rem & 31;
        w2t[o * 4096 + i * 128 + h] = w2[idx];
    } else if (b < 1137) {
        int e = (b - 512) * 256 + t;
        if (e < NE) atomicAdd(&cnt[ei[NE + e]], 1);
    } else if (b < 2387) {
        int idx = (b - 1137) * 256 + t;              // < NN*DIM
        int n = idx >> 5, d = idx & 31;
        out[idx] = fmaxf(x[n] * lw[d] + lb[d], 0.f);
    } else {
        if (t <= NG) {
            int g = t, lo = 0, hi = NN;
            while (lo < hi) { int mid = (lo + hi) >> 1; if (batch[mid] < g) lo = mid + 1; else hi = mid; }
            gstart[g] = lo;
        }
    }
}

__global__ void k_scan(const int* __restrict__ cnt, int* __restrict__ row_start,
                       float* __restrict__ deg) {
    __shared__ int sums[256];
    int t = threadIdx.x;
    const int chunk = (NN + 255) / 256;   // 40
    int begin = t * chunk;
    int end = begin + chunk; if (end > NN) end = NN;
    int s = 0;
    for (int i = begin; i < end; ++i) s += cnt[i];
    sums[t] = s;
    __syncthreads();
    if (t == 0) {
        int acc = 0;
        for (int i = 0; i < 256; ++i) { int v = sums[i]; sums[i] = acc; acc += v; }
        row_start[NN] = acc;   // == NE
    }
    __syncthreads();
    int acc = sums[t];
    for (int i = begin; i < end; ++i) {
        row_start[i] = acc;
        int c = cnt[i];
        deg[i] = (float)(c > 0 ? c : 1);
        acc += c;
    }
}

// sort edge payloads by dst so the conv edge loop reads wave-uniform sequential data
__global__ void k_fill(const int* __restrict__ ei, const float* __restrict__ ea,
                       const int* __restrict__ row_start, int* __restrict__ cursor,
                       int* __restrict__ srt_src, float* __restrict__ srt_ea) {
    int e = blockIdx.x * 256 + threadIdx.x;
    if (e >= NE) return;
    int d = ei[NE + e];
    int p = atomicAdd(&cursor[d], 1);
    int pos = row_start[d] + p;
    srt_src[pos] = ei[e];
    srt_ea[2 * pos]     = ea[2 * e];
    srt_ea[2 * pos + 1] = ea[2 * e + 1];
}

// ---------------------------------------------------------------- NNConv + GRU fused
__global__ __launch_bounds__(256, 4) void k_conv_gru(
    const int* __restrict__ row_start, const int* __restrict__ srt_src,
    const float* __restrict__ srt_ea,
    const float* __restrict__ w1, const float* __restrict__ b1,
    const float* __restrict__ w2t, const float* __restrict__ b2,
    const float* __restrict__ out_old, const float* __restrict__ deg,
    float* __restrict__ Sg,
    const float* __restrict__ root, const float* __restrict__ cbias,
    const float* __restrict__ wih, const float* __restrict__ whh,
    const float* __restrict__ bih, const float* __restrict__ bhh,
    float* __restrict__ out_new)
{
    __shared__ float R[4 * 16 * 128];   // [nb][i_half][h] = 32 KB
    int t = threadIdx.x;
    int wave = t >> 6, lane = t & 63;
    int n0 = blockIdx.x * 4;
    int n = n0 + wave;

    // ---------------- edge phase ----------------
    float Racc[64];
    #pragma unroll
    for (int i = 0; i < 64; ++i) Racc[i] = 0.f;
    float sacc = 0.f;

    float w1a0 = w1[lane],      w1c0 = w1[128 + lane],  bb0 = b1[lane];
    float w1a1 = w1[64 + lane], w1c1 = w1[192 + lane],  bb1 = b1[64 + lane];

    int rs = row_start[n], re = row_start[n + 1];
    const float2* eap = (const float2*)srt_ea;
    for (int p = rs; p < re; ++p) {
        int src = srt_src[p];                       // wave-uniform
        float2 a = eap[p];
        float r0 = fmaxf(a.x * w1a0 + a.y * w1c0 + bb0, 0.f);
        float r1 = fmaxf(a.x * w1a1 + a.y * w1c1 + bb1, 0.f);
        const float4* op = (const float4*)(out_old + src * DIM);
        #pragma unroll
        for (int q = 0; q < 8; ++q) {
            float4 o4 = op[q];
            Racc[4 * q + 0]      += r0 * o4.x;
            Racc[4 * q + 1]      += r0 * o4.y;
            Racc[4 * q + 2]      += r0 * o4.z;
            Racc[4 * q + 3]      += r0 * o4.w;
            Racc[32 + 4 * q + 0] += r1 * o4.x;
            Racc[32 + 4 * q + 1] += r1 * o4.y;
            Racc[32 + 4 * q + 2] += r1 * o4.z;
            Racc[32 + 4 * q + 3] += r1 * o4.w;
        }
        if (lane < DIM) sacc += out_old[src * DIM + lane];
    }
    if (lane < DIM) Sg[n * DIM + lane] = sacc;

    // ---------------- contraction (two i-halves) ----------------
    int og = t >> 5, cp = t & 31;                  // o-tile og*4..+3, h-float4 cp
    float acc[4][4];
    #pragma unroll
    for (int a = 0; a < 4; ++a)
        #pragma unroll
        for (int b = 0; b < 4; ++b) acc[a][b] = 0.f;

    float* Rw = R + wave * 16 * 128;
    const float4* Rv = (const float4*)R;
    const float4* Wv = (const float4*)w2t;

    #pragma unroll
    for (int half = 0; half < 2; ++half) {
        if (half) __syncthreads();                 // prior half's reads done
        #pragma unroll
        for (int q = half * 4; q < half * 4 + 4; ++q) {
            #pragma unroll
            for (int j = 0; j < 4; ++j) {
                int li = 4 * q + j - half * 16;    // 0..15
                Rw[li * 128 + lane]      = Racc[4 * q + j];        // h=lane (2-way free)
                Rw[li * 128 + 64 + lane] = Racc[32 + 4 * q + j];   // h=lane+64
            }
        }
        __syncthreads();
        #pragma unroll 2
        for (int i = 0; i < 16; ++i) {
            int rb = i * 32 + cp;
            float4 r0 = Rv[rb];
            float4 r1 = Rv[512 + rb];
            float4 r2 = Rv[1024 + rb];
            float4 r3 = Rv[1536 + rb];
            int gi = half * 16 + i;
            #pragma unroll
            for (int ot = 0; ot < 4; ++ot) {
                float4 w = Wv[(og * 4 + ot) * 1024 + gi * 32 + cp];
                acc[0][ot] += r0.x * w.x + r0.y * w.y + r0.z * w.z + r0.w * w.w;
                acc[1][ot] += r1.x * w.x + r1.y * w.y + r1.z * w.z + r1.w * w.w;
                acc[2][ot] += r2.x * w.x + r2.y * w.y + r2.z * w.z + r2.w * w.w;
                acc[3][ot] += r3.x * w.x + r3.y * w.y + r3.z * w.z + r3.w * w.w;
            }
        }
    }
    #pragma unroll
    for (int s = 1; s < 32; s <<= 1) {
        #pragma unroll
        for (int nb = 0; nb < 4; ++nb)
            #pragma unroll
            for (int ot = 0; ot < 4; ++ot)
                acc[nb][ot] += __shfl_xor(acc[nb][ot], s);
    }
    __syncthreads();                               // all R reads complete
    if (cp == 0) {                                 // stash agg into R[0..127]
        #pragma unroll
        for (int nb = 0; nb < 4; ++nb)
            #pragma unroll
            for (int ot = 0; ot < 4; ++ot)
                R[nb * 32 + og * 4 + ot] = acc[nb][ot];
    }
    __syncthreads();

    // ---------------- fused GRU epilogue (threads 0..127) ----------------
    if (t < 128) {
        int nb = t >> 5, d = t & 31, nn_ = n0 + nb;
        int base = t & 32;                          // shfl base within wave
        float aggv = R[nb * 32 + d];
        float bt = 0.f;
        #pragma unroll 8
        for (int i = 0; i < DIM; ++i) bt += Sg[nn_ * DIM + i] * b2[i * DIM + d];
        aggv = (aggv + bt) / deg[nn_];

        float x = out_old[nn_ * DIM + d];           // h_old[d]
        float rootsum = 0.f;
        #pragma unroll 8
        for (int k = 0; k < DIM; ++k)
            rootsum += __shfl(x, base + k) * root[k * DIM + d];
        float m = fmaxf(aggv + rootsum + cbias[d], 0.f);

        float gir = bih[d], giz = bih[DIM + d], gin = bih[2 * DIM + d];
        float ghr = bhh[d], ghz = bhh[DIM + d], ghn = bhh[2 * DIM + d];
        #pragma unroll 4
        for (int k = 0; k < DIM; ++k) {
            float mk = __shfl(m, base + k);
            float hk = __shfl(x, base + k);
            gir += mk * wih[k * 96 + d];
            giz += mk * wih[k * 96 + DIM + d];
            gin += mk * wih[k * 96 + 2 * DIM + d];
            ghr += hk * whh[k * 96 + d];
            ghz += hk * whh[k * 96 + DIM + d];
            ghn += hk * whh[k * 96 + 2 * DIM + d];
        }
        float rg = sigmoidf_(gir + ghr);
        float zg = sigmoidf_(giz + ghz);
        float ng = tanhf(gin + rg * ghn);
        out_new[nn_ * DIM + d] = (1.f - zg) * ng + zg * x;
    }
}

// ---------------------------------------------------------------- Set2Set + head
// One block per graph. LSTM weights preloaded to LDS; shuffle-based reductions
// (2 barriers each instead of 8-barrier trees); rvec via (stripe,dim) register
// accumulation + one LDS combine (no atomics).
__global__ __launch_bounds__(256) void k_set2set(
    const float* __restrict__ out, const int* __restrict__ gstart,
    const float* __restrict__ wih, const float* __restrict__ whh,
    const float* __restrict__ bih, const float* __restrict__ bhh,
    const float* __restrict__ l1w, const float* __restrict__ l1b,
    const float* __restrict__ l2w, const float* __restrict__ l2b,
    float* __restrict__ ebuf, float* __restrict__ y)
{
    __shared__ float swih[64 * 128];   // 32 KB
    __shared__ float swhh[32 * 128];   // 16 KB
    __shared__ float sq[2 * DIM];
    __shared__ float shh[DIM], scc[DIM];
    __shared__ float sgates[4 * DIM];
    __shared__ float sacc[8][DIM];
    __shared__ float sredA[4], sredB[4];

    int g = blockIdx.x, t = threadIdx.x;
    // coalesced weight preload
    {
        const float4* wv = (const float4*)wih;   float4* sv = (float4*)swih;
        for (int i = t; i < 2048; i += 256) sv[i] = wv[i];
        const float4* wv2 = (const float4*)whh;  float4* sv2 = (float4*)swhh;
        for (int i = t; i < 1024; i += 256) sv2[i] = wv2[i];
    }
    if (t < 2 * DIM) sq[t] = 0.f;
    if (t < DIM) { shh[t] = 0.f; scc[t] = 0.f; }
    int ns = gstart[g], ne = gstart[g + 1];
    __syncthreads();

    for (int step = 0; step < 3; ++step) {
        // ---- LSTM gates (threads 0..127), weights in LDS ----
        if (t < 128) {
            float acc = bih[t] + bhh[t];
            #pragma unroll 8
            for (int k = 0; k < 2 * DIM; ++k) acc += sq[k] * swih[k * 128 + t];
            #pragma unroll 8
            for (int k = 0; k < DIM; ++k)     acc += shh[k] * swhh[k * 128 + t];
            sgates[t] = acc;
        }
        __syncthreads();
        if (t < DIM) {
            float ig = sigmoidf_(sgates[t]);
            float fg = sigmoidf_(sgates[DIM + t]);
            float gg = tanhf(sgates[2 * DIM + t]);
            float og = sigmoidf_(sgates[3 * DIM + t]);
            float c_new = fg * scc[t] + ig * gg;
            float h_new = og * tanhf(c_new);
            scc[t] = c_new;
            shh[t] = h_new;
            sq[t] = h_new;
        }
        __syncthreads();

        // ---- e = <out_n, q>, max via shuffle ----
        float lmax = -3.0e38f;
        for (int n = ns + t; n < ne; n += 256) {
            const float4* orow = (const float4*)(out + n * DIM);
            float e = 0.f;
            #pragma unroll
            for (int q = 0; q < 8; ++q) {
                float4 o4 = orow[q];
                e += o4.x * shh[4 * q] + o4.y * shh[4 * q + 1]
                   + o4.z * shh[4 * q + 2] + o4.w * shh[4 * q + 3];
            }
            ebuf[n] = e;
            lmax = fmaxf(lmax, e);
        }
        #pragma unroll
        for (int s = 1; s < 64; s <<= 1) lmax = fmaxf(lmax, __shfl_xor(lmax, s));
        if ((t & 63) == 0) sredA[t >> 6] = lmax;
        __syncthreads();
        float M = fmaxf(fmaxf(sredA[0], sredA[1]), fmaxf(sredA[2], sredA[3]));

        // ---- exp + sum via shuffle ----
        float lsum = 0.f;
        for (int n = ns + t; n < ne; n += 256) {
            float v = expf(ebuf[n] - M);
            ebuf[n] = v;
            lsum += v;
        }
        #pragma unroll
        for (int s = 1; s < 64; s <<= 1) lsum += __shfl_xor(lsum, s);
        if ((t & 63) == 0) sredB[t >> 6] = lsum;
        __syncthreads();
        float S = sredB[0] + sredB[1] + sredB[2] + sredB[3];
        float inv = (S > 0.f) ? 1.f / S : 0.f;

        // ---- rvec: stripe=t>>5 over nodes, d=t&31; no atomics ----
        int stp = t >> 5, d = t & 31;
        float racc = 0.f;
        for (int n = ns + stp; n < ne; n += 8)
            racc += ebuf[n] * out[n * DIM + d];
        sacc[stp][d] = racc;
        __syncthreads();
        if (t < DIM) {
            float r = 0.f;
            #pragma unroll
            for (int s = 0; s < 8; ++s) r += sacc[s][t];
            sq[DIM + t] = r * inv;
        }
        __syncthreads();
    }

    // ---- head: y[g] = relu(q_star @ l1w + l1b) @ l2w + l2b ----
    if (t < DIM) {
        float h = l1b[t];
        #pragma unroll 8
        for (int k = 0; k < 2 * DIM; ++k) h += sq[k] * l1w[k * DIM + t];
        float v = fmaxf(h, 0.f) * l2w[t];
        #pragma unroll
        for (int s = 1; s < 32; s <<= 1) v += __shfl_xor(v, s);
        if (t == 0) y[g] = v + l2b[0];
    }
}

// ---------------------------------------------------------------- launch
extern "C" void kernel_launch(void* const* d_in, const int* in_sizes, int n_in,
                              void* d_out, int out_size, void* d_ws, size_t ws_size,
                              hipStream_t stream) {
    const float* x         = (const float*)d_in[0];
    const float* edge_attr = (const float*)d_in[1];
    const float* lin0_w    = (const float*)d_in[2];
    const float* lin0_b    = (const float*)d_in[3];
    const float* nn_w1     = (const float*)d_in[4];
    const float* nn_b1     = (const float*)d_in[5];
    const float* nn_w2     = (const float*)d_in[6];
    const float* nn_b2     = (const float*)d_in[7];
    const float* conv_root = (const float*)d_in[8];
    const float* conv_bias = (const float*)d_in[9];
    const float* gru_w_ih  = (const float*)d_in[10];
    const float* gru_w_hh  = (const float*)d_in[11];
    const float* gru_b_ih  = (const float*)d_in[12];
    const float* gru_b_hh  = (const float*)d_in[13];
    const float* lstm_w_ih = (const float*)d_in[14];
    const float* lstm_w_hh = (const float*)d_in[15];
    const float* lstm_b_ih = (const float*)d_in[16];
    const float* lstm_b_hh = (const float*)d_in[17];
    const float* lin1_w    = (const float*)d_in[18];
    const float* lin1_b    = (const float*)d_in[19];
    const float* lin2_w    = (const float*)d_in[20];
    const float* lin2_b    = (const float*)d_in[21];
    const int*   edge_index= (const int*)d_in[22];
    const int*   batch     = (const int*)d_in[23];
    float* yout = (float*)d_out;

    char* p = (char*)d_ws;
    auto alloc = [&](size_t bytes) { char* r = p; p += (bytes + 255) & ~(size_t)255; return r; };

    // ---- zero region (one memset) ----
    int*   cnt    = (int*)  alloc(NN * sizeof(int));
    int*   cursor = (int*)  alloc(NN * sizeof(int));
    size_t zero_bytes = (size_t)(p - (char*)d_ws);
    // ---- rest ----
    int*   row_start = (int*)  alloc((NN + 1) * sizeof(int));
    int*   gstart    = (int*)  alloc((NG + 1) * sizeof(int));
    int*   srt_src   = (int*)  alloc(NE * sizeof(int));
    float* srt_ea    = (float*)alloc(2 * NE * sizeof(float));
    float* deg       = (float*)alloc(NN * sizeof(float));
    float* outA      = (float*)alloc(NN * DIM * sizeof(float));
    float* outB      = (float*)alloc(NN * DIM * sizeof(float));
    float* Sg        = (float*)alloc(NN * DIM * sizeof(float));
    float* w2t       = (float*)alloc(128 * 1024 * sizeof(float));
    float* ebuf      = (float*)alloc(NN * sizeof(float));
    (void)ws_size; (void)n_in; (void)in_sizes; (void)out_size;

    hipMemsetAsync(d_ws, 0, zero_bytes, stream);

    k_setup<<<2388, 256, 0, stream>>>(nn_w2, w2t, edge_index, cnt,
                                      x, lin0_w, lin0_b, outA, batch, gstart);
    k_scan <<<1,    256, 0, stream>>>(cnt, row_start, deg);
    k_fill <<<625,  256, 0, stream>>>(edge_index, edge_attr, row_start, cursor, srt_src, srt_ea);

    const float* cur = outA;
    float* nxt = outB;
    for (int it = 0; it < 3; ++it) {
        k_conv_gru<<<2500, 256, 0, stream>>>(row_start, srt_src, srt_ea,
                                             nn_w1, nn_b1, w2t, nn_b2,
                                             cur, deg, Sg,
                                             conv_root, conv_bias,
                                             gru_w_ih, gru_w_hh, gru_b_ih, gru_b_hh,
                                             nxt);
        const float* tmp = nxt; nxt = (float*)cur; cur = tmp;
    }
    const float* outF = cur;

    k_set2set<<<NG, 256, 0, stream>>>(outF, gstart,
                                      lstm_w_ih, lstm_w_hh, lstm_b_ih, lstm_b_hh,
                                      lin1_w, lin1_b, lin2_w, lin2_b, ebuf, yout);
}